// Round 8
// baseline (138.652 us; speedup 1.0000x reference)
//
#include <hip/hip_runtime.h>

#define CUTOFF 5.0f
#define DEPS 1e-12f
#define FSQRT(x) __builtin_amdgcn_sqrtf(x)

// ws float layout (first 136 floats zeroed by hipMemsetAsync each launch):
//  acc[0]      ligand coord-loss sum of per-batch ratios
//  acc[1]      (as uint) done-block counter
//  acc[3..6]   sidechain mse, am, val, has sums
//  [8, 72)     bnum[64]  per-batch ligand pair num (triangular: half of ref sums)
//  [72, 136)   bden[64]  per-batch ligand pair den

#define NSC_BLK 512   // blocks [0,512): sidechain, 128 groups each (2 lanes/group)
#define NLIG_BLK 512  // blocks [512,1024): ligand, 64 batches * 8 balanced tile-pairs
#define GRID (NSC_BLK + NLIG_BLK)

__global__ __launch_bounds__(256) void fused_kernel(
    const float* __restrict__ lig_pred, const float* __restrict__ lig_tgt,
    const int* __restrict__ lig_mask,
    const float* __restrict__ sc_pred, const float* __restrict__ sc_tgt,
    const int* __restrict__ sc_mask,
    float* __restrict__ ws, float* __restrict__ out) {
  const int tid = threadIdx.x;
  float* bnum = ws + 8;
  float* bden = ws + 72;
  unsigned int* done = (unsigned int*)(ws + 1);

  __shared__ float4 stage4[1344];  // 21.5 KB, sidechain staging only
  __shared__ float red[4][4];
  __shared__ bool last;

  if (blockIdx.x < NSC_BLK) {
    // ================= sidechain: 2 lanes per group (R4/R7 path, verified) =================
    const int sb = blockIdx.x;
    float ax[7], ay[7], az[7];  // pred, own atoms
    float bx[7], by[7], bz[7];  // tgt, own atoms
    float m[7];

    const float4* srcp = (const float4*)(sc_pred + (size_t)sb * 5376);
    for (int k = tid; k < 1344; k += 256) stage4[k] = srcp[k];
    __syncthreads();
    {
      const float* s = ((const float*)stage4) + tid * 21;  // gcd(21,32)=1: no conflicts
#pragma unroll
      for (int a = 0; a < 7; a++) { ax[a] = s[3 * a]; ay[a] = s[3 * a + 1]; az[a] = s[3 * a + 2]; }
    }
    __syncthreads();
    const float4* srct = (const float4*)(sc_tgt + (size_t)sb * 5376);
    for (int k = tid; k < 1344; k += 256) stage4[k] = srct[k];
    __syncthreads();
    {
      const float* s = ((const float*)stage4) + tid * 21;
#pragma unroll
      for (int a = 0; a < 7; a++) { bx[a] = s[3 * a]; by[a] = s[3 * a + 1]; bz[a] = s[3 * a + 2]; }
    }
    const int* mp = sc_mask + (size_t)sb * 1792 + tid * 7;
#pragma unroll
    for (int a = 0; a < 7; a++) m[a] = (mp[a] != 0) ? 1.f : 0.f;

    float mse = 0.f, am = 0.f;
#pragma unroll
    for (int a = 0; a < 7; a++) {
      float dx = ax[a] - bx[a], dy = ay[a] - by[a], dz = az[a] - bz[a];
      mse += m[a] * ((dx * dx + dy * dy + dz * dz) * (1.f / 3.f));
      am += m[a];
    }

    float num = 0.f, den = 0.f;
#pragma unroll
    for (int js = 0; js < 7; js++) {
#pragma unroll
      for (int side = 0; side < 2; side++) {
        float jx, jy, jz, kx, ky, kz, mj;
        if (side == 0) {
          jx = ax[js]; jy = ay[js]; jz = az[js];
          kx = bx[js]; ky = by[js]; kz = bz[js];
          mj = m[js];
        } else {
          jx = __shfl_xor(ax[js], 1, 64); jy = __shfl_xor(ay[js], 1, 64);
          jz = __shfl_xor(az[js], 1, 64);
          kx = __shfl_xor(bx[js], 1, 64); ky = __shfl_xor(by[js], 1, 64);
          kz = __shfl_xor(bz[js], 1, 64);
          mj = __shfl_xor(m[js], 1, 64);
        }
#pragma unroll
        for (int i = 0; i < 7; i++) {
          float dx = bx[i] - kx, dy = by[i] - ky, dz = bz[i] - kz;
          float tsq = dx * dx + dy * dy + dz * dz;
          float td = FSQRT(fmaxf(tsq, DEPS));
          float w = m[i] * mj;
          w = (tsq > 0.f) ? w : 0.f;
          w = (td <= CUTOFF) ? w : 0.f;
          float qx = ax[i] - jx, qy = ay[i] - jy, qz = az[i] - jz;
          float pd = FSQRT(fmaxf(qx * qx + qy * qy + qz * qz, DEPS));
          float d = pd - td;
          num += w * d * d;
          den += w;
        }
      }
    }
    float num_g = num + __shfl_xor(num, 1, 64);
    float den_g = den + __shfl_xor(den, 1, 64);
    float val = (den_g > 0.f) ? 0.5f * (num_g / fmaxf(den_g, 1.f)) : 0.f;
    float has = (den_g > 0.f) ? 0.5f : 0.f;

    for (int off = 32; off > 0; off >>= 1) {
      mse += __shfl_down(mse, off, 64);
      am += __shfl_down(am, off, 64);
      val += __shfl_down(val, off, 64);
      has += __shfl_down(has, off, 64);
    }
    int lane = tid & 63, wv = tid >> 6;
    if (lane == 0) { red[0][wv] = mse; red[1][wv] = am; red[2][wv] = val; red[3][wv] = has; }
    __syncthreads();
    if (tid == 0) {
      atomicAdd(&ws[3], red[0][0] + red[0][1] + red[0][2] + red[0][3]);
      atomicAdd(&ws[4], red[1][0] + red[1][1] + red[1][2] + red[1][3]);
      atomicAdd(&ws[5], red[2][0] + red[2][1] + red[2][2] + red[2][3]);
      atomicAdd(&ws[6], red[3][0] + red[3][1] + red[3][2] + red[3][3]);
    }
  } else {
    // ====== ligand, triangular + balanced tile-pairs {t, 15-t}; NO LDS ======
    // i-atom data is wave-uniform -> scalar-cache loads; j-atoms coalesced v-loads.
    const int L = 512;
    const int lb = blockIdx.x - NSC_BLK;  // 0..511
    const int b = lb >> 3;
    const int t = lb & 7;
    const int i0a = 32 * t;
    const int i0b = 32 * (15 - t);
    const float* pb = lig_pred + (size_t)b * L * 3;
    const float* tb = lig_tgt + (size_t)b * L * 3;
    const int* mb = lig_mask + (size_t)b * L;

    float num0 = 0.f, den0 = 0.f, num1 = 0.f, den1 = 0.f, se = 0.f, cnt = 0.f;

    // ---- tileA: js in [i0a, 512) ----
#pragma unroll
    for (int k = 0; k < 2; k++) {
      const int js = i0a + (k << 8) + tid;
      if (js < L) {  // wave-uniform except one boundary wave
        float pjx = pb[3 * js], pjy = pb[3 * js + 1], pjz = pb[3 * js + 2];
        float tjx = tb[3 * js], tjy = tb[3 * js + 1], tjz = tb[3 * js + 2];
        float mj = (mb[js] != 0) ? 1.f : 0.f;
        if (t == 0) {  // t==0: slots k=0,1 cover all 512 atoms exactly once
          float dx = pjx - tjx, dy = pjy - tjy, dz = pjz - tjz;
          se += mj * (dx * dx + dy * dy + dz * dz);
          cnt += mj;
        }
#pragma unroll
        for (int ii = 0; ii < 32; ii++) {
          const int i = i0a + ii;  // uniform index -> scalar loads
          float tix = tb[3 * i], tiy = tb[3 * i + 1], tiz = tb[3 * i + 2];
          float pix = pb[3 * i], piy = pb[3 * i + 1], piz = pb[3 * i + 2];
          float mi = (mb[i] != 0) ? 1.f : 0.f;
          float w = (js > i) ? mi * mj : 0.f;  // triangular gate
          float dx = tix - tjx, dy = tiy - tjy, dz = tiz - tjz;
          float tsq = dx * dx + dy * dy + dz * dz;
          float td = FSQRT(fmaxf(tsq, DEPS));
          w = (tsq > 0.f) ? w : 0.f;
          w = (td <= CUTOFF) ? w : 0.f;
          float qx = pix - pjx, qy = piy - pjy, qz = piz - pjz;
          float pd = FSQRT(fmaxf(qx * qx + qy * qy + qz * qz, DEPS));
          float d = pd - td;
          if (ii & 1) { num1 += w * d * d; den1 += w; }
          else        { num0 += w * d * d; den0 += w; }
        }
      }
    }

    // ---- tileB: js in [i0b, 512) ----
    {
      const int js = i0b + tid;
      if (js < L) {
        float pjx = pb[3 * js], pjy = pb[3 * js + 1], pjz = pb[3 * js + 2];
        float tjx = tb[3 * js], tjy = tb[3 * js + 1], tjz = tb[3 * js + 2];
        float mj = (mb[js] != 0) ? 1.f : 0.f;
#pragma unroll
        for (int ii = 0; ii < 32; ii++) {
          const int i = i0b + ii;
          float tix = tb[3 * i], tiy = tb[3 * i + 1], tiz = tb[3 * i + 2];
          float pix = pb[3 * i], piy = pb[3 * i + 1], piz = pb[3 * i + 2];
          float mi = (mb[i] != 0) ? 1.f : 0.f;
          float w = (js > i) ? mi * mj : 0.f;
          float dx = tix - tjx, dy = tiy - tjy, dz = tiz - tjz;
          float tsq = dx * dx + dy * dy + dz * dz;
          float td = FSQRT(fmaxf(tsq, DEPS));
          w = (tsq > 0.f) ? w : 0.f;
          w = (td <= CUTOFF) ? w : 0.f;
          float qx = pix - pjx, qy = piy - pjy, qz = piz - pjz;
          float pd = FSQRT(fmaxf(qx * qx + qy * qy + qz * qz, DEPS));
          float d = pd - td;
          if (ii & 1) { num1 += w * d * d; den1 += w; }
          else        { num0 += w * d * d; den0 += w; }
        }
      }
    }

    float num = num0 + num1, den = den0 + den1;
    for (int off = 32; off > 0; off >>= 1) {
      num += __shfl_down(num, off, 64);
      den += __shfl_down(den, off, 64);
      se += __shfl_down(se, off, 64);
      cnt += __shfl_down(cnt, off, 64);
    }
    int lane = tid & 63, wv = tid >> 6;
    if (lane == 0) { red[0][wv] = num; red[1][wv] = den; red[2][wv] = se; red[3][wv] = cnt; }
    __syncthreads();
    if (tid == 0) {
      atomicAdd(&bnum[b], red[0][0] + red[0][1] + red[0][2] + red[0][3]);
      atomicAdd(&bden[b], red[1][0] + red[1][1] + red[1][2] + red[1][3]);
      if (t == 0) {
        float se_t = red[2][0] + red[2][1] + red[2][2] + red[2][3];
        float cnt_t = red[3][0] + red[3][1] + red[3][2] + red[3][3];
        atomicAdd(&ws[0], se_t / (3.f * fmaxf(cnt_t, 1.f)));
      }
    }
  }

  // ---------------- last-block finalize (R3-proven pattern) ----------------
  if (tid == 0) {
    __threadfence();
    unsigned int old = atomicAdd(done, 1u);
    last = (old == GRID - 1);
  }
  __syncthreads();
  if (last) {
    __threadfence();
    if (tid < 64) {
      // atomic read-backs: device-scope coherent view of other blocks' adds
      float n = atomicAdd(&bnum[tid], 0.f);
      float d = atomicAdd(&bden[tid], 0.f);
      float val = (d > 0.f) ? n / fmaxf(d, 1.f) : 0.f;
      float has = (d > 0.f) ? 1.f : 0.f;
      for (int off = 32; off > 0; off >>= 1) {
        val += __shfl_down(val, off, 64);
        has += __shfl_down(has, off, 64);
      }
      if (tid == 0) {
        float lig = atomicAdd(&ws[0], 0.f) * (1.f / 64.f);
        float sc_mse = atomicAdd(&ws[3], 0.f);
        float sc_am = atomicAdd(&ws[4], 0.f);
        float sc_val = atomicAdd(&ws[5], 0.f);
        float sc_has = atomicAdd(&ws[6], 0.f);
        float ligand_dist_loss = val / fmaxf(has, 1.f);
        float sidechain_loss = sc_mse / fmaxf(sc_am, 1.f);
        float sidechain_dist_loss = sc_val / fmaxf(sc_has, 1.f);
        out[0] = lig + 0.2f * ligand_dist_loss + 0.5f * sidechain_loss +
                 0.1f * sidechain_dist_loss;
      }
    }
  }
}

extern "C" void kernel_launch(void* const* d_in, const int* in_sizes, int n_in,
                              void* d_out, int out_size, void* d_ws, size_t ws_size,
                              hipStream_t stream) {
  const float* ligand_pred = (const float*)d_in[0];
  const float* ligand_tgt = (const float*)d_in[1];
  const float* sidechain_pred = (const float*)d_in[2];
  const float* sidechain_tgt = (const float*)d_in[3];
  const int* ligand_mask = (const int*)d_in[4];
  const int* atom_mask = (const int*)d_in[5];
  float* out = (float*)d_out;
  float* ws = (float*)d_ws;

  hipMemsetAsync(ws, 0, 136 * sizeof(float), stream);  // accumulators + counter
  fused_kernel<<<GRID, 256, 0, stream>>>(ligand_pred, ligand_tgt, ligand_mask,
                                         sidechain_pred, sidechain_tgt, atom_mask,
                                         ws, out);
}